// Round 4
// baseline (1740.903 us; speedup 1.0000x reference)
//
#include <hip/hip_runtime.h>

#define NG 4096
#define NP 512
#define BSZ 128
#define NT 100

typedef _Float16 f16;
typedef __attribute__((ext_vector_type(8))) _Float16 half8;
typedef __attribute__((ext_vector_type(4))) _Float16 half4v;
typedef __attribute__((ext_vector_type(16))) float f32x16;

__device__ inline f32x16 mfma16(half8 a, half8 b, f32x16 c) {
  return __builtin_amdgcn_mfma_f32_32x32x16_f16(a, b, c, 0, 0, 0);
}
__device__ __forceinline__ void gload16(const void* g, void* l) {
  __builtin_amdgcn_global_load_lds(
      (const __attribute__((address_space(1))) void*)g,
      (__attribute__((address_space(3))) void*)l, 16, 0, 0);
}

// ---------------- prep: f32 -> fp16 ----------------
__global__ __launch_bounds__(256) void conv_f16(
    const float* __restrict__ src, f16* __restrict__ dst, int n4)
{
  int i = blockIdx.x * 256 + threadIdx.x;
  if (i >= n4) return;
  const float4 x = ((const float4*)src)[i];
  half4v h = { (f16)x.x, (f16)x.y, (f16)x.z, (f16)x.w };
  *(half4v*)&dst[(size_t)i * 4] = h;
}

// ---------------- K-split fp16 GEMM (step + encode) ----------------
// part[bx][m][n] = sum_{k in slice bx} A[m][k] * B[n][k]
// grid (KSn, 32); 512 thr = 8 waves = 2 K-groups x (2M x 2N of 64x64).
// LDS: dbuf 2x32KB (A[128][128B] + B[128][128B], XOR-swizzled via global
// source, rule #21) + 32KB f16 out-bounce. Group-1 acc merged via f32
// exchange in dbuf region; store is LDS-bounced for 16B/lane coalescing.
__global__ __launch_bounds__(512, 1) void gemm_ksplit(
    const f16* __restrict__ bmat, const f16* __restrict__ amat,
    f16* __restrict__ part, int krow, int kblk, int nch)
{
  __shared__ __align__(128) char lds[98304];
  const int tid = threadIdx.x;
  const int w = tid >> 6, lane = tid & 63;
  const int g = w >> 2, s = w & 3, wm = s & 1, wn = s >> 1;
  const int l31 = lane & 31, hi = lane >> 5;
  const int n0 = blockIdx.y * 128;
  const size_t krb = (size_t)krow * 2;

  const int lrow = lane >> 3, lu = lane & 7;
  const int sw = (lu ^ lrow) * 16;
  const char* gA = (const char*)amat;
  const char* gB = (const char*)bmat + (size_t)n0 * krb;

  f32x16 acc[2][2] = {};

  auto stage = [&](int buf, int c) {
    const size_t kb = (size_t)((blockIdx.x * kblk + c * 64) * 2) + sw;
    char* lb = lds + buf * 32768;
    #pragma unroll
    for (int i = 0; i < 2; ++i) {
      const int r = w * 8 + i * 64;
      gload16(gA + (size_t)(r + lrow) * krb + kb, lb + r * 128);
      gload16(gB + (size_t)(r + lrow) * krb + kb, lb + 16384 + r * 128);
    }
  };
  auto compute = [&](int buf) {
    const char* bA = lds + buf * 32768;
    const char* bB = bA + 16384;
    const int swr = (lane & 7) << 4;
    #pragma unroll
    for (int kk = 0; kk < 2; ++kk) {
      const int bc = (g * 64 + kk * 32 + (hi << 4)) ^ swr;
      half8 a0 = *(const half8*)(bA + (wm * 64 + l31) * 128 + bc);
      half8 a1 = *(const half8*)(bA + (wm * 64 + 32 + l31) * 128 + bc);
      half8 b0 = *(const half8*)(bB + (wn * 64 + l31) * 128 + bc);
      half8 b1 = *(const half8*)(bB + (wn * 64 + 32 + l31) * 128 + bc);
      acc[0][0] = mfma16(a0, b0, acc[0][0]);
      acc[0][1] = mfma16(a0, b1, acc[0][1]);
      acc[1][0] = mfma16(a1, b0, acc[1][0]);
      acc[1][1] = mfma16(a1, b1, acc[1][1]);
    }
  };

  stage(0, 0);
  __syncthreads();
  #pragma unroll 1
  for (int c = 0; c < nch; ++c) {
    if (c + 1 < nch) stage((c + 1) & 1, c + 1);
    compute(c & 1);
    __syncthreads();
  }

  // ---- merge group 1 -> group 0, f16 bounce, coalesced store ----
  // C/D 32x32 frag: col = lane&31, row = (q&3)+8*(q>>2)+4*(lane>>5)
  float* ex = (float*)lds;
  f16* exh = (f16*)(lds + 65536);
  if (g == 1) {
    #pragma unroll
    for (int mf = 0; mf < 2; ++mf)
      #pragma unroll
      for (int nf = 0; nf < 2; ++nf)
        #pragma unroll
        for (int q = 0; q < 16; ++q) {
          const int row = wm * 64 + mf * 32 + (q & 3) + 8 * (q >> 2) + 4 * hi;
          const int col = wn * 64 + nf * 32 + l31;
          ex[row * 128 + col] = acc[mf][nf][q];
        }
  }
  __syncthreads();
  if (g == 0) {
    #pragma unroll
    for (int mf = 0; mf < 2; ++mf)
      #pragma unroll
      for (int nf = 0; nf < 2; ++nf)
        #pragma unroll
        for (int q = 0; q < 16; ++q) {
          const int row = wm * 64 + mf * 32 + (q & 3) + 8 * (q >> 2) + 4 * hi;
          const int col = wn * 64 + nf * 32 + l31;
          exh[row * 128 + col] = (f16)(acc[mf][nf][q] + ex[row * 128 + col]);
        }
  }
  __syncthreads();
  f16* po = part + (size_t)blockIdx.x * (BSZ * NG) + n0;
  const int ur = tid >> 4, uu = tid & 15;
  #pragma unroll
  for (int i = 0; i < 4; ++i) {
    const int r = i * 32 + ur;
    *(half8*)(po + (size_t)r * NG + uu * 8) = *(const half8*)(exh + r * 128 + uu * 8);
  }
}

// sum nsets fp16 partials (+ optional vin bias + relu) -> f16
__global__ __launch_bounds__(256) void reduce_kernel(
    const f16* __restrict__ part, const float* __restrict__ v,
    const float* __restrict__ wih, f16* __restrict__ hout,
    int t, int nsets, int dobias)
{
  const int i = blockIdx.x * 256 + threadIdx.x;   // 65536 threads x 8 elems
  const int b = i >> 9;
  const int gi = (i & 511) * 8;
  const half8* p = (const half8*)part + (((size_t)b * NG + gi) >> 3);
  float s[8];
  half8 q0 = p[0];
  #pragma unroll
  for (int j = 0; j < 8; ++j) s[j] = (float)q0[j];
  #pragma unroll 1
  for (int k = 1; k < nsets; ++k) {
    half8 q = p[(size_t)k * (BSZ * NG / 8)];
    #pragma unroll
    for (int j = 0; j < 8; ++j) s[j] += (float)q[j];
  }
  half8 h;
  if (dobias) {
    const float2 vb = *(const float2*)&v[((size_t)b * NT + t) * 2];
    const float4* wr = (const float4*)(wih + (size_t)gi * 2);
    #pragma unroll
    for (int j2 = 0; j2 < 4; ++j2) {
      const float4 ww = wr[j2];
      h[j2 * 2]     = (f16)fmaxf(s[j2 * 2]     + vb.x * ww.x + vb.y * ww.y, 0.f);
      h[j2 * 2 + 1] = (f16)fmaxf(s[j2 * 2 + 1] + vb.x * ww.z + vb.y * ww.w, 0.f);
    }
  } else {
    #pragma unroll
    for (int j = 0; j < 8; ++j) h[j] = (f16)s[j];
  }
  *(half8*)&hout[(size_t)b * NG + gi] = h;
}

// ---------------- decode + fused log_softmax (unchanged, verified r3) ----------------
__global__ __launch_bounds__(512, 2) void decode_kernel(
    const f16* __restrict__ hs, const f16* __restrict__ wdec16,
    float* __restrict__ out)
{
  __shared__ __align__(128) char lds[2 * 73728];
  __shared__ float redm[8][64];
  __shared__ float reds[8][64];
  __shared__ float gLS[64];
  const int tid = threadIdx.x;
  const int w = tid >> 6, lane = tid & 63;
  const int l31 = lane & 31, hi = lane >> 5;
  const int r0 = blockIdx.x * 64;

  const int lrow8 = lane >> 3;
  const int swz = ((lane & 7) ^ lrow8) * 16;
  const char* gA = (const char*)(hs + (size_t)r0 * NG);
  const char* gB = (const char*)wdec16;

  f32x16 acc[2][2] = {};

  auto stage = [&](int buf, int c) {
    const size_t kb = (size_t)(c * 128) + swz;
    char* lb = lds + buf * 73728;
    gload16(gA + (size_t)(w * 8 + lrow8) * (NG * 2) + kb, lb + w * 1024);
    #pragma unroll
    for (int j = 0; j < 8; ++j) {
      const int r = w * 64 + j * 8;
      gload16(gB + (size_t)(r + lrow8) * (NG * 2) + kb, lb + 8192 + r * 128);
    }
  };
  auto compute = [&](int buf) {
    const char* bA = lds + buf * 73728;
    const char* bB = bA + 8192;
    const int swr = (lane & 7) << 4;
    #pragma unroll
    for (int kk = 0; kk < 4; ++kk) {
      const int bc = (kk * 32 + (hi << 4)) ^ swr;
      half8 a0 = *(const half8*)(bA + l31 * 128 + bc);
      half8 a1 = *(const half8*)(bA + (32 + l31) * 128 + bc);
      half8 b0 = *(const half8*)(bB + (w * 64 + l31) * 128 + bc);
      half8 b1 = *(const half8*)(bB + (w * 64 + 32 + l31) * 128 + bc);
      acc[0][0] = mfma16(a0, b0, acc[0][0]);
      acc[0][1] = mfma16(a0, b1, acc[0][1]);
      acc[1][0] = mfma16(a1, b0, acc[1][0]);
      acc[1][1] = mfma16(a1, b1, acc[1][1]);
    }
  };

  stage(0, 0);
  __syncthreads();
  #pragma unroll 1
  for (int c = 0; c < 64; ++c) {
    if (c < 63) stage((c + 1) & 1, c + 1);
    compute(c & 1);
    __syncthreads();
  }

  #pragma unroll
  for (int mf = 0; mf < 2; ++mf) {
    #pragma unroll
    for (int q = 0; q < 16; ++q) {
      float m = fmaxf(acc[mf][0][q], acc[mf][1][q]);
      #pragma unroll
      for (int d = 1; d < 32; d <<= 1) m = fmaxf(m, __shfl_xor(m, d));
      if (l31 == q) redm[w][mf * 32 + (q & 3) + 8 * (q >> 2) + 4 * hi] = m;
    }
  }
  __syncthreads();
  if (tid < 64) {
    float M = redm[0][tid];
    #pragma unroll
    for (int ww = 1; ww < 8; ++ww) M = fmaxf(M, redm[ww][tid]);
    gLS[tid] = M;
  }
  __syncthreads();
  #pragma unroll
  for (int mf = 0; mf < 2; ++mf) {
    #pragma unroll
    for (int q = 0; q < 16; ++q) {
      const int rl = mf * 32 + (q & 3) + 8 * (q >> 2) + 4 * hi;
      const float M = gLS[rl];
      float e = __expf(acc[mf][0][q] - M) + __expf(acc[mf][1][q] - M);
      #pragma unroll
      for (int d = 1; d < 32; d <<= 1) e += __shfl_xor(e, d);
      if (l31 == q) reds[w][rl] = e;
    }
  }
  __syncthreads();
  if (tid < 64) {
    float S = reds[0][tid];
    #pragma unroll
    for (int ww = 1; ww < 8; ++ww) S += reds[ww][tid];
    gLS[tid] = gLS[tid] + __logf(S);
  }
  __syncthreads();
  #pragma unroll
  for (int mf = 0; mf < 2; ++mf) {
    #pragma unroll
    for (int q = 0; q < 16; ++q) {
      const int rl = mf * 32 + (q & 3) + 8 * (q >> 2) + 4 * hi;
      const int r = r0 + rl;
      const int tt = r >> 7, b = r & 127;
      const float lg = gLS[rl];
      float* orow = out + ((size_t)b * NT + tt) * NP + w * 64 + l31;
      orow[0]  = acc[mf][0][q] - lg;
      orow[32] = acc[mf][1][q] - lg;
    }
  }
}

// ---------------- host ----------------

extern "C" void kernel_launch(void* const* d_in, const int* in_sizes, int n_in,
                              void* d_out, int out_size, void* d_ws, size_t ws_size,
                              hipStream_t stream)
{
  const float* v    = (const float*)d_in[0];
  const float* p0   = (const float*)d_in[1];
  const float* wenc = (const float*)d_in[2];
  const float* wih  = (const float*)d_in[3];
  const float* whh  = (const float*)d_in[4];
  const float* wdec = (const float*)d_in[5];
  float* out = (float*)d_out;
  char* ws = (char*)d_ws;

  f16* whh16  = (f16*)(ws);                 // 33,554,432 B
  f16* wdec16 = (f16*)(ws + 33554432);      //  4,194,304 B
  f16* h016   = (f16*)(ws + 37748736);      //  1,048,576 B
  f16* p016   = (f16*)(ws + 38797312);      //    131,072 B
  f16* hs     = (f16*)(ws + 38928384);      // 104,857,600 B
  f16* part   = (f16*)d_out;                // <= 8.4 MB f16 scratch until decode
  const size_t BNG = (size_t)BSZ * NG;

  conv_f16<<<dim3(16384), dim3(256), 0, stream>>>(whh, whh16, 4194304);
  conv_f16<<<dim3(2048), dim3(256), 0, stream>>>(wdec, wdec16, 524288);
  conv_f16<<<dim3(64), dim3(256), 0, stream>>>(p0, p016, 16384);
  conv_f16<<<dim3(4096), dim3(256), 0, stream>>>(wenc, (f16*)(ws + 143785984), 524288);
  f16* wenc16 = (f16*)(ws + 143785984);     // 4,194,304 B (tail of ws)

  // encode: h0 = p0 @ Wenc^T via the same K-split GEMM (K=512, KS=2)
  gemm_ksplit<<<dim3(2, 32), dim3(512), 0, stream>>>(wenc16, p016, part, NP, 256, 4);
  reduce_kernel<<<dim3(256), dim3(256), 0, stream>>>(part, v, wih, h016, 0, 2, 0);

  for (int t = 0; t < NT; ++t) {
    const f16* hp = (t == 0) ? h016 : hs + (size_t)(t - 1) * BNG;
    gemm_ksplit<<<dim3(8, 32), dim3(512), 0, stream>>>(whh16, hp, part, NG, 512, 8);
    reduce_kernel<<<dim3(256), dim3(256), 0, stream>>>(part, v, wih, hs + (size_t)t * BNG, t, 8, 1);
  }
  decode_kernel<<<dim3(200), dim3(512), 0, stream>>>(hs, wdec16, out);
}